// Round 4
// baseline (528355.615 us; speedup 1.0000x reference)
//
#include <hip/hip_runtime.h>

#define HID 2048
#define IN_DIM 512
#define TSTEPS 1024
#define NBLK 256
#define NTHR 256
#define KS 66   // padded chunk stride in floats (64+2): 2-way banks = free, 8B aligned

typedef unsigned long long ull;
typedef unsigned int u32;

__device__ __forceinline__ float reduce32(float v) {
    v += __shfl_xor(v, 16, 64);
    v += __shfl_xor(v, 8, 64);
    v += __shfl_xor(v, 4, 64);
    v += __shfl_xor(v, 2, 64);
    v += __shfl_xor(v, 1, 64);
    return v;
}

__global__ void __launch_bounds__(NTHR, 1)
ode_rnn_main(const float* __restrict__ x, const float* __restrict__ t,
             const float* __restrict__ W_in, const float* __restrict__ b_in,
             const float* __restrict__ W_hid, const float* __restrict__ b_hid,
             const float* __restrict__ W_ode, const float* __restrict__ b_ode,
             const float* __restrict__ W_dec, const float* __restrict__ b_dec,
             const int* __restrict__ nstep_p,
             ull* __restrict__ kb,          // kb[2][HID] tagged (round<<32|float) words
             float* __restrict__ out)
{
    __shared__ float k_lds[2][32 * KS];
    __shared__ u32 cnt[32];                // monotone per-chunk arrival counters

    const int tid = threadIdx.x;
    const int bid = blockIdx.x;
    const int g   = tid & 31;              // lane in group == column-chunk index
    const int grp = tid >> 5;              // 0..7
    const int row = bid * 8 + grp;
    const int nstep = *nstep_p;

    if (tid < 32) cnt[tid] = 0;

    // ---- per-lane weights: W_ode[row][g*64 .. g*64+64), W_in[row][g*16 .. +16) ----
    float wode[64];
    {
        const float* wr = W_ode + (size_t)row * HID + g * 64;
#pragma unroll
        for (int q = 0; q < 16; ++q) {
            float4 v = *(const float4*)(wr + 4 * q);
            wode[4*q+0] = v.x; wode[4*q+1] = v.y;
            wode[4*q+2] = v.z; wode[4*q+3] = v.w;
        }
    }
    float win[16];
    {
        const float* wr = W_in + (size_t)row * IN_DIM + g * 16;
#pragma unroll
        for (int q = 0; q < 4; ++q) {
            float4 v = *(const float4*)(wr + 4 * q);
            win[4*q+0] = v.x; win[4*q+1] = v.y;
            win[4*q+2] = v.z; win[4*q+3] = v.w;
        }
    }
    const float breg = b_ode[row];
    const float bsum = b_in[row] + b_hid[row];

    float h[64];                           // replicated h for my 64 columns

    __syncthreads();                       // cnt init visible before any bump

    // ---- poll duty: my 8 global words for round p; batched unconditional loads ----
    auto duty = [&](u32 p) {
        ull* src = kb + (size_t)(p & 1u) * HID + tid * 8;
        float v[8];
        for (;;) {
            ull w[8];
#pragma unroll
            for (int e = 0; e < 8; ++e)
                w[e] = __hip_atomic_load(&src[e], __ATOMIC_RELAXED,
                                         __HIP_MEMORY_SCOPE_AGENT);
            bool ok = true;
#pragma unroll
            for (int e = 0; e < 8; ++e) ok &= ((u32)(w[e] >> 32) == p);
            if (ok) {
#pragma unroll
                for (int e = 0; e < 8; ++e) v[e] = __uint_as_float((u32)w[e]);
                break;
            }
            __builtin_amdgcn_s_sleep(1);
        }
        float* dst = &k_lds[p & 1u][(tid >> 3) * KS + (tid & 7) * 8];
#pragma unroll
        for (int e = 0; e < 8; ++e) dst[e] = v[e];
        __hip_atomic_fetch_add(&cnt[tid >> 3], 1u, __ATOMIC_RELEASE,
                               __HIP_MEMORY_SCOPE_WORKGROUP);
    };
    auto gate = [&](u32 p) {
        const u32 need = 8u * p;
        while (__hip_atomic_load(&cnt[g], __ATOMIC_ACQUIRE,
                                 __HIP_MEMORY_SCOPE_WORKGROUP) < need) { }
    };
    auto emit = [&](u32 p1, float y) {
        if (g == 0) {
            ull pv = ((ull)p1 << 32) | (ull)__float_as_uint(y);
            __hip_atomic_store(kb + (size_t)(p1 & 1u) * HID + row, pv,
                               __ATOMIC_RELAXED, __HIP_MEMORY_SCOPE_AGENT);
        }
    };

    // consume a k-round: w = W_ode_row . k  (and h += coef*k)
    auto consume_k = [&](u32 p, float coef) -> float {
        duty(p); gate(p);
        const float* base = &k_lds[p & 1u][g * KS];
        float a0 = 0.f, a1 = 0.f, a2 = 0.f, a3 = 0.f;
#pragma unroll
        for (int m = 0; m < 16; ++m) {
            float2 q0 = *(const float2*)(base + 4 * m);
            float2 q1 = *(const float2*)(base + 4 * m + 2);
            a0 = fmaf(wode[4*m+0], q0.x, a0);
            a1 = fmaf(wode[4*m+1], q0.y, a1);
            a2 = fmaf(wode[4*m+2], q1.x, a2);
            a3 = fmaf(wode[4*m+3], q1.y, a3);
            h[4*m+0] = fmaf(coef, q0.x, h[4*m+0]);
            h[4*m+1] = fmaf(coef, q0.y, h[4*m+1]);
            h[4*m+2] = fmaf(coef, q1.x, h[4*m+2]);
            h[4*m+3] = fmaf(coef, q1.y, h[4*m+3]);
        }
        return reduce32((a0 + a1) + (a2 + a3));
    };

    // consume a broadcast-h round: h = v, u = W_ode_row . v
    auto consume_set = [&](u32 p) -> float {
        duty(p); gate(p);
        const float* base = &k_lds[p & 1u][g * KS];
        float a0 = 0.f, a1 = 0.f, a2 = 0.f, a3 = 0.f;
#pragma unroll
        for (int m = 0; m < 16; ++m) {
            float2 q0 = *(const float2*)(base + 4 * m);
            float2 q1 = *(const float2*)(base + 4 * m + 2);
            h[4*m+0] = q0.x; h[4*m+1] = q0.y;
            h[4*m+2] = q1.x; h[4*m+3] = q1.y;
            a0 = fmaf(wode[4*m+0], q0.x, a0);
            a1 = fmaf(wode[4*m+1], q0.y, a1);
            a2 = fmaf(wode[4*m+2], q1.x, a2);
            a3 = fmaf(wode[4*m+3], q1.y, a3);
        }
        return reduce32((a0 + a1) + (a2 + a3));
    };

    // consume k4 of the LAST substep: h += dt6*k4, then W_hid.h + W_in.x_i
    auto consume_k4last = [&](u32 p, float coef, int i) -> float {
        // prefetch W_hid row chunk + x_i chunk (in flight during polling)
        const float* wr = W_hid + (size_t)row * HID + g * 64;
        float4 whv[16];
#pragma unroll
        for (int q = 0; q < 16; ++q) whv[q] = *(const float4*)(wr + 4 * q);
        const float* xr = x + (size_t)i * IN_DIM + g * 16;
        float4 xv[4];
#pragma unroll
        for (int q = 0; q < 4; ++q) xv[q] = *(const float4*)(xr + 4 * q);

        duty(p); gate(p);
        const float* base = &k_lds[p & 1u][g * KS];
#pragma unroll
        for (int m = 0; m < 16; ++m) {
            float2 q0 = *(const float2*)(base + 4 * m);
            float2 q1 = *(const float2*)(base + 4 * m + 2);
            h[4*m+0] = fmaf(coef, q0.x, h[4*m+0]);
            h[4*m+1] = fmaf(coef, q0.y, h[4*m+1]);
            h[4*m+2] = fmaf(coef, q1.x, h[4*m+2]);
            h[4*m+3] = fmaf(coef, q1.y, h[4*m+3]);
        }
        float a0 = 0.f, a1 = 0.f, a2 = 0.f, a3 = 0.f;
#pragma unroll
        for (int q = 0; q < 16; ++q) {
            a0 = fmaf(whv[q].x, h[4*q+0], a0);
            a1 = fmaf(whv[q].y, h[4*q+1], a1);
            a2 = fmaf(whv[q].z, h[4*q+2], a2);
            a3 = fmaf(whv[q].w, h[4*q+3], a3);
        }
#pragma unroll
        for (int q = 0; q < 4; ++q) {
            a0 = fmaf(win[4*q+0], xv[q].x, a0);
            a1 = fmaf(win[4*q+1], xv[q].y, a1);
            a2 = fmaf(win[4*q+2], xv[q].z, a2);
            a3 = fmaf(win[4*q+3], xv[q].w, a3);
        }
        return reduce32((a0 + a1) + (a2 + a3));
    };

    // ---- round 1: emit h0 = tanh(W_in x0 + b_in + b_hid) ----
    {
        const float* xr = x + g * 16;
        float a = 0.f;
#pragma unroll
        for (int q = 0; q < 4; ++q) {
            float4 v = *(const float4*)(xr + 4 * q);
            a = fmaf(win[4*q+0], v.x, a);
            a = fmaf(win[4*q+1], v.y, a);
            a = fmaf(win[4*q+2], v.z, a);
            a = fmaf(win[4*q+3], v.w, a);
        }
        emit(1, tanhf(reduce32(a) + bsum));
    }
    // consume h0: set h, build u; emit k1 of (i=1,s=0)
    float u_ = consume_set(1);
    float ub = u_ + breg;
    emit(2, tanhf(ub));
    u32 p = 2;

    for (int i = 1; i < TSTEPS; ++i) {
        const float dt  = (t[i] - t[i - 1]) / (float)nstep;
        const float dt2 = 0.5f * dt;
        const float dt3 = dt * (1.0f / 3.0f);
        const float dt6 = dt * (1.0f / 6.0f);

        for (int s = 0; s < nstep; ++s) {
            const bool last = (s == nstep - 1);
            float w1 = consume_k(p, dt6); emit(p + 1, tanhf(ub + dt2 * w1)); ++p;
            float w2 = consume_k(p, dt3); emit(p + 1, tanhf(ub + dt2 * w2)); ++p;
            float w3 = consume_k(p, dt3); emit(p + 1, tanhf(ub + dt  * w3)); ++p;
            if (!last) {
                float w4 = consume_k(p, dt6);
                u_ += dt6 * (w1 + 2.f * (w2 + w3) + w4);
                ub  = u_ + breg;
                emit(p + 1, tanhf(ub)); ++p;
            } else {
                float r = consume_k4last(p, dt6, i);
                emit(p + 1, tanhf(r + bsum)); ++p;   // h_next broadcast
            }
        }
        if (i < TSTEPS - 1) {
            u_ = consume_set(p); ub = u_ + breg;
            emit(p + 1, tanhf(ub)); ++p;             // k1 of next timestep
        } else {
            (void)consume_set(p); ++p;               // final h into regs
        }
    }

    // ---- decode: out = W_dec @ h_final + b_dec (blocks 0..63) ----
    if (bid < 64) {
        const int r2 = bid * 8 + grp;
        const float* wd = W_dec + (size_t)r2 * HID + g * 64;
        float a0 = 0.f, a1 = 0.f, a2 = 0.f, a3 = 0.f;
#pragma unroll
        for (int q = 0; q < 16; ++q) {
            float4 wv = *(const float4*)(wd + 4 * q);
            a0 = fmaf(wv.x, h[4*q+0], a0);
            a1 = fmaf(wv.y, h[4*q+1], a1);
            a2 = fmaf(wv.z, h[4*q+2], a2);
            a3 = fmaf(wv.w, h[4*q+3], a3);
        }
        float r = reduce32((a0 + a1) + (a2 + a3));
        if (g == 0) out[r2] = r + b_dec[r2];
    }
}

extern "C" void kernel_launch(void* const* d_in, const int* in_sizes, int n_in,
                              void* d_out, int out_size, void* d_ws, size_t ws_size,
                              hipStream_t stream) {
    const float* x     = (const float*)d_in[0];
    const float* t     = (const float*)d_in[1];
    const float* W_in  = (const float*)d_in[2];
    const float* b_in  = (const float*)d_in[3];
    const float* W_hid = (const float*)d_in[4];
    const float* b_hid = (const float*)d_in[5];
    const float* W_ode = (const float*)d_in[6];
    const float* b_ode = (const float*)d_in[7];
    const float* W_dec = (const float*)d_in[8];
    const float* b_dec = (const float*)d_in[9];
    const int*   nstep = (const int*)d_in[10];
    ull* kb = (ull*)d_ws;                  // 2 * 2048 * 8B = 32 KB (poison-safe tags)
    float* out = (float*)d_out;

    ode_rnn_main<<<dim3(NBLK), dim3(NTHR), 0, stream>>>(
        x, t, W_in, b_in, W_hid, b_hid, W_ode, b_ode, W_dec, b_dec,
        nstep, kb, out);
}

// Round 5
// 337636.816 us; speedup vs baseline: 1.5649x; 1.5649x over previous
//
#include <hip/hip_runtime.h>

#define HID 2048
#define IN_DIM 512
#define TSTEPS 1024
#define NBLK 256
#define NTHR 256
#define KS 66   // chunk stride (floats): 2-way bank alias = free, 8B aligned

typedef unsigned long long ull;
typedef unsigned int u32;

__device__ __forceinline__ float reduce32(float v) {
    v += __shfl_xor(v, 16, 64);
    v += __shfl_xor(v, 8, 64);
    v += __shfl_xor(v, 4, 64);
    v += __shfl_xor(v, 2, 64);
    v += __shfl_xor(v, 1, 64);
    return v;
}

__global__ void __launch_bounds__(NTHR, 1)
ode_rnn_main(const float* __restrict__ x, const float* __restrict__ t,
             const float* __restrict__ W_in, const float* __restrict__ b_in,
             const float* __restrict__ W_hid, const float* __restrict__ b_hid,
             const float* __restrict__ W_ode, const float* __restrict__ b_ode,
             const float* __restrict__ W_dec, const float* __restrict__ b_dec,
             const int* __restrict__ nstep_p,
             ull* __restrict__ kb,          // kb[2][HID] tagged (round<<32|bits)
             float* __restrict__ out)
{
    __shared__ float k_lds[2][32 * KS];
    __shared__ u32 cnt[32];        // monotone per-chunk arrival counters
    __shared__ float gv[8];        // per-block row-leader gather
    __shared__ u32 gcnt;           // monotone emission arrivals
    __shared__ u32 clk;            // monotone clock flag

    const int tid = threadIdx.x;
    const int bid = blockIdx.x;
    const int g   = tid & 31;      // lane in 32-group == column-chunk index
    const int grp = tid >> 5;      // 0..7
    const int row = bid * 8 + grp;
    const int nstep = *nstep_p;
    const int clkline = (bid + 1) & (NBLK - 1);

    if (tid < 32) cnt[tid] = 0;
    if (tid == 0) { gcnt = 0; clk = 0; }

    // ---- per-lane weights ----
    float wode[64];
    {
        const float* wr = W_ode + (size_t)row * HID + g * 64;
#pragma unroll
        for (int q = 0; q < 16; ++q) {
            float4 v = *(const float4*)(wr + 4 * q);
            wode[4*q+0] = v.x; wode[4*q+1] = v.y;
            wode[4*q+2] = v.z; wode[4*q+3] = v.w;
        }
    }
    float win[16];
    {
        const float* wr = W_in + (size_t)row * IN_DIM + g * 16;
#pragma unroll
        for (int q = 0; q < 4; ++q) {
            float4 v = *(const float4*)(wr + 4 * q);
            win[4*q+0] = v.x; win[4*q+1] = v.y;
            win[4*q+2] = v.z; win[4*q+3] = v.w;
        }
    }
    const float breg = b_ode[row];
    const float bsum = b_in[row] + b_hid[row];

    float h[64];
    __syncthreads();               // cnt/gcnt/clk init visible

    // ---- emission: row-leaders gather in LDS; 8th arrival stores the line ----
    auto emit = [&](u32 p1, float y) {
        if (g == 0) {
            gv[grp] = y;
            u32 old = __hip_atomic_fetch_add(&gcnt, 1u, __ATOMIC_ACQ_REL,
                                             __HIP_MEMORY_SCOPE_WORKGROUP);
            if (old == 8u * p1 - 1u) {         // last of this emission
                ull* dst = kb + (size_t)(p1 & 1u) * HID + (size_t)bid * 8;
#pragma unroll
                for (int e = 0; e < 8; ++e) {
                    ull pv = ((ull)p1 << 32) | (ull)__float_as_uint(gv[e]);
                    __hip_atomic_store(&dst[e], pv, __ATOMIC_RELAXED,
                                       __HIP_MEMORY_SCOPE_AGENT);
                }
            }
        }
    };

    // ---- wait: clock (wave0, 1 word) -> LDS flag -> one bulk sweep -> gate ----
    auto wait_all = [&](u32 p) {
        if (tid < 64) {
            // whole wave 0 polls the same remote word: uniform loop, 1 req/iter
            ull* cw = kb + (size_t)(p & 1u) * HID + (size_t)clkline * 8;
            while ((u32)(__hip_atomic_load(cw, __ATOMIC_RELAXED,
                                           __HIP_MEMORY_SCOPE_AGENT) >> 32) != p) { }
            if (tid == 0)
                __hip_atomic_store(&clk, p, __ATOMIC_RELEASE,
                                   __HIP_MEMORY_SCOPE_WORKGROUP);
        }
        while (__hip_atomic_load(&clk, __ATOMIC_ACQUIRE,
                                 __HIP_MEMORY_SCOPE_WORKGROUP) < p) { }

        ull* src = kb + (size_t)(p & 1u) * HID + (size_t)tid * 8;
        ull w[8];
        for (;;) {
#pragma unroll
            for (int e = 0; e < 8; ++e)
                w[e] = __hip_atomic_load(&src[e], __ATOMIC_RELAXED,
                                         __HIP_MEMORY_SCOPE_AGENT);
            bool ok = true;
#pragma unroll
            for (int e = 0; e < 8; ++e) ok &= ((u32)(w[e] >> 32) == p);
            if (ok) break;
            __builtin_amdgcn_s_sleep(1);      // straggler window only
        }
        float* dst = &k_lds[p & 1u][(tid >> 3) * KS + (tid & 7) * 8];
#pragma unroll
        for (int e = 0; e < 8; ++e) dst[e] = __uint_as_float((u32)w[e]);
        __hip_atomic_fetch_add(&cnt[tid >> 3], 1u, __ATOMIC_RELEASE,
                               __HIP_MEMORY_SCOPE_WORKGROUP);
        const u32 need = 8u * p;
        while (__hip_atomic_load(&cnt[g], __ATOMIC_ACQUIRE,
                                 __HIP_MEMORY_SCOPE_WORKGROUP) < need) { }
    };

    auto dot_chunk = [&](u32 p) -> float {
        const float* base = &k_lds[p & 1u][g * KS];
        float a0 = 0.f, a1 = 0.f, a2 = 0.f, a3 = 0.f;
#pragma unroll
        for (int m = 0; m < 16; ++m) {
            float2 q0 = *(const float2*)(base + 4 * m);
            float2 q1 = *(const float2*)(base + 4 * m + 2);
            a0 = fmaf(wode[4*m+0], q0.x, a0);
            a1 = fmaf(wode[4*m+1], q0.y, a1);
            a2 = fmaf(wode[4*m+2], q1.x, a2);
            a3 = fmaf(wode[4*m+3], q1.y, a3);
        }
        return reduce32((a0 + a1) + (a2 + a3));
    };
    auto h_axpy = [&](u32 p, float coef) {     // off critical path (after emit)
        const float* base = &k_lds[p & 1u][g * KS];
#pragma unroll
        for (int m = 0; m < 32; ++m) {
            float2 q = *(const float2*)(base + 2 * m);
            h[2*m+0] = fmaf(coef, q.x, h[2*m+0]);
            h[2*m+1] = fmaf(coef, q.y, h[2*m+1]);
        }
    };
    auto h_set = [&](u32 p) {
        const float* base = &k_lds[p & 1u][g * KS];
#pragma unroll
        for (int m = 0; m < 32; ++m) {
            float2 q = *(const float2*)(base + 2 * m);
            h[2*m+0] = q.x; h[2*m+1] = q.y;
        }
    };

    // ---- round 1: h0 = tanh(W_in x0 + b_in + b_hid) ----
    {
        const float* xr = x + g * 16;
        float a = 0.f;
#pragma unroll
        for (int q = 0; q < 4; ++q) {
            float4 v = *(const float4*)(xr + 4 * q);
            a = fmaf(win[4*q+0], v.x, a);
            a = fmaf(win[4*q+1], v.y, a);
            a = fmaf(win[4*q+2], v.z, a);
            a = fmaf(win[4*q+3], v.w, a);
        }
        emit(1, tanhf(reduce32(a) + bsum));
    }
    wait_all(1);
    float u_ = dot_chunk(1);
    float ub = u_ + breg;
    emit(2, tanhf(ub));            // k1 of (i=1, s=0)
    h_set(1);
    u32 p = 2;

    for (int i = 1; i < TSTEPS; ++i) {
        const float dt  = (t[i] - t[i - 1]) / (float)nstep;
        const float dt2 = 0.5f * dt;
        const float dt3 = dt * (1.0f / 3.0f);
        const float dt6 = dt * (1.0f / 6.0f);

        for (int s = 0; s < nstep; ++s) {
            const bool last = (s == nstep - 1);
            float w1, w2, w3;
            wait_all(p); w1 = dot_chunk(p);
            emit(p + 1, tanhf(ub + dt2 * w1)); h_axpy(p, dt6); ++p;
            wait_all(p); w2 = dot_chunk(p);
            emit(p + 1, tanhf(ub + dt2 * w2)); h_axpy(p, dt3); ++p;
            wait_all(p); w3 = dot_chunk(p);
            emit(p + 1, tanhf(ub + dt  * w3)); h_axpy(p, dt3); ++p;
            if (!last) {
                wait_all(p); float w4 = dot_chunk(p);
                u_ += dt6 * (w1 + 2.f * (w2 + w3) + w4);
                ub  = u_ + breg;
                emit(p + 1, tanhf(ub)); h_axpy(p, dt6); ++p;
            } else {
                // prefetch W_hid row + x_i while waiting
                const float* wr = W_hid + (size_t)row * HID + g * 64;
                float4 whv[16];
#pragma unroll
                for (int q = 0; q < 16; ++q) whv[q] = *(const float4*)(wr + 4 * q);
                const float* xr = x + (size_t)i * IN_DIM + g * 16;
                float4 xv[4];
#pragma unroll
                for (int q = 0; q < 4; ++q) xv[q] = *(const float4*)(xr + 4 * q);

                wait_all(p);
                h_axpy(p, dt6);               // fold k4 (needed before W_hid.h)
                float a0 = 0.f, a1 = 0.f, a2 = 0.f, a3 = 0.f;
#pragma unroll
                for (int q = 0; q < 16; ++q) {
                    a0 = fmaf(whv[q].x, h[4*q+0], a0);
                    a1 = fmaf(whv[q].y, h[4*q+1], a1);
                    a2 = fmaf(whv[q].z, h[4*q+2], a2);
                    a3 = fmaf(whv[q].w, h[4*q+3], a3);
                }
#pragma unroll
                for (int q = 0; q < 4; ++q) {
                    a0 = fmaf(win[4*q+0], xv[q].x, a0);
                    a1 = fmaf(win[4*q+1], xv[q].y, a1);
                    a2 = fmaf(win[4*q+2], xv[q].z, a2);
                    a3 = fmaf(win[4*q+3], xv[q].w, a3);
                }
                float r = reduce32((a0 + a1) + (a2 + a3));
                emit(p + 1, tanhf(r + bsum)); ++p;   // h_next broadcast
            }
        }
        if (i < TSTEPS - 1) {
            wait_all(p); u_ = dot_chunk(p); ub = u_ + breg;
            emit(p + 1, tanhf(ub)); h_set(p); ++p;   // k1 of next timestep
        } else {
            // final h broadcast at round p: only decode blocks consume
            if (bid < 64) {
                wait_all(p);
                const int r2 = bid * 8 + grp;
                const float* wd = W_dec + (size_t)r2 * HID + g * 64;
                const float* base = &k_lds[p & 1u][g * KS];
                float a0 = 0.f, a1 = 0.f, a2 = 0.f, a3 = 0.f;
#pragma unroll
                for (int m = 0; m < 16; ++m) {
                    float2 q0 = *(const float2*)(base + 4 * m);
                    float2 q1 = *(const float2*)(base + 4 * m + 2);
                    a0 = fmaf(wd[4*m+0], q0.x, a0);
                    a1 = fmaf(wd[4*m+1], q0.y, a1);
                    a2 = fmaf(wd[4*m+2], q1.x, a2);
                    a3 = fmaf(wd[4*m+3], q1.y, a3);
                }
                float r = reduce32((a0 + a1) + (a2 + a3));
                if (g == 0) out[r2] = r + b_dec[r2];
            }
            ++p;
        }
    }
}

extern "C" void kernel_launch(void* const* d_in, const int* in_sizes, int n_in,
                              void* d_out, int out_size, void* d_ws, size_t ws_size,
                              hipStream_t stream) {
    const float* x     = (const float*)d_in[0];
    const float* t     = (const float*)d_in[1];
    const float* W_in  = (const float*)d_in[2];
    const float* b_in  = (const float*)d_in[3];
    const float* W_hid = (const float*)d_in[4];
    const float* b_hid = (const float*)d_in[5];
    const float* W_ode = (const float*)d_in[6];
    const float* b_ode = (const float*)d_in[7];
    const float* W_dec = (const float*)d_in[8];
    const float* b_dec = (const float*)d_in[9];
    const int*   nstep = (const int*)d_in[10];
    ull* kb = (ull*)d_ws;                  // 2*2048*8B = 32 KB; 0xAA poison != any tag
    float* out = (float*)d_out;

    ode_rnn_main<<<dim3(NBLK), dim3(NTHR), 0, stream>>>(
        x, t, W_in, b_in, W_hid, b_hid, W_ode, b_ode, W_dec, b_dec,
        nstep, kb, out);
}